// Round 1
// baseline (191.734 us; speedup 1.0000x reference)
//
#include <hip/hip_runtime.h>
#include <stdint.h>

#define M_DIM 2048
#define K_DIM 4096
#define N_DIM 11008

typedef int v4i __attribute__((ext_vector_type(4)));

// ---------------- workspace layout ----------------
// [0]        : 2 floats  (x_scale, x_scale*y_scale)
// [1024]     : 1024 float partial maxima
// [65536]    : x_q   int8 [M*K]            = 8,388,608 B
// [8454144]  : w_t   int8 [N*K] (transposed, packed) = 45,088,768 B
#define WS_XQ_OFF   65536ull
#define WS_WT_OFF   8454144ull
#define WS_FULL_BYTES (8454144ull + 45088768ull)
#define WS_SMALL_BYTES 8454144ull

static __device__ __forceinline__ void llds16(const void* g, void* l) {
  __builtin_amdgcn_global_load_lds(
      reinterpret_cast<const uint32_t __attribute__((address_space(1)))*>(
          reinterpret_cast<uintptr_t>(g)),
      reinterpret_cast<uint32_t __attribute__((address_space(3)))*>(
          reinterpret_cast<uintptr_t>(l)),
      16, 0, 0);
}

// ---------------- kernel 1: per-block abs-max over x ----------------
__global__ __launch_bounds__(256) void absmax_kernel(const float* __restrict__ x,
                                                     float* __restrict__ part) {
  __shared__ float red[256];
  const int g = blockIdx.x * 256 + threadIdx.x;
  const float4* x4 = reinterpret_cast<const float4*>(x);
  float m = 0.f;
#pragma unroll
  for (int i = 0; i < 8; ++i) {
    float4 v = x4[(size_t)i * 262144 + g];
    m = fmaxf(m, fmaxf(fmaxf(fabsf(v.x), fabsf(v.y)),
                       fmaxf(fabsf(v.z), fabsf(v.w))));
  }
  red[threadIdx.x] = m;
  __syncthreads();
  for (int s = 128; s > 0; s >>= 1) {
    if (threadIdx.x < s) red[threadIdx.x] = fmaxf(red[threadIdx.x], red[threadIdx.x + s]);
    __syncthreads();
  }
  if (threadIdx.x == 0) part[blockIdx.x] = red[0];
}

// ---------------- kernel 2: finalize scales ----------------
__global__ __launch_bounds__(256) void finalize_scale(const float* __restrict__ part,
                                                      const float* __restrict__ y_scale,
                                                      float* __restrict__ scales) {
  __shared__ float red[256];
  const int t = threadIdx.x;
  float m = fmaxf(fmaxf(part[t], part[t + 256]), fmaxf(part[t + 512], part[t + 768]));
  red[t] = m;
  __syncthreads();
  for (int s = 128; s > 0; s >>= 1) {
    if (t < s) red[t] = fmaxf(red[t], red[t + s]);
    __syncthreads();
  }
  if (t == 0) {
    float xs = red[0] * (1.0f / 128.0f);  // exact (pow2)
    scales[0] = xs;
    scales[1] = xs * y_scale[0];
  }
}

// ---------------- kernel 3: quantize x -> int8 ----------------
__global__ __launch_bounds__(256) void quant_kernel(const float* __restrict__ x,
                                                    const float* __restrict__ scales,
                                                    signed char* __restrict__ xq) {
  const float s = scales[0];
  const size_t t = (size_t)blockIdx.x * 256 + threadIdx.x;
  const float4* x4 = reinterpret_cast<const float4*>(x) + t * 4;
  v4i o;
#pragma unroll
  for (int i = 0; i < 4; ++i) {
    float4 v = x4[i];
    int q0 = (int)rintf(v.x / s);  // matches np.round (half-to-even)
    int q1 = (int)rintf(v.y / s);
    int q2 = (int)rintf(v.z / s);
    int q3 = (int)rintf(v.w / s);
    q0 = max(-128, min(127, q0));
    q1 = max(-128, min(127, q1));
    q2 = max(-128, min(127, q2));
    q3 = max(-128, min(127, q3));
    o[i] = (q0 & 255) | ((q1 & 255) << 8) | ((q2 & 255) << 16) | ((q3 & 255) << 24);
  }
  *reinterpret_cast<v4i*>(xq + t * 16) = o;
}

// ---------------- kernel 4: transpose+pack w32[K,N] -> w_t int8[N,K] ----------------
__global__ __launch_bounds__(256) void transpose_pack(const int* __restrict__ w,
                                                      signed char* __restrict__ wt) {
  __shared__ int tile[64 * 65];  // [k][n], pad 65 -> conflict-free column reads
  const int t = threadIdx.x;
  const int n0 = blockIdx.x * 64;
  const int k0 = blockIdx.y * 64;
#pragma unroll
  for (int p = 0; p < 4; ++p) {
    const int id = p * 256 + t;
    const int r = id >> 4;    // k row 0..63
    const int c4 = id & 15;   // group of 4 n
    v4i v = *reinterpret_cast<const v4i*>(w + (size_t)(k0 + r) * N_DIM + n0 + c4 * 4);
    tile[r * 65 + c4 * 4 + 0] = v[0];
    tile[r * 65 + c4 * 4 + 1] = v[1];
    tile[r * 65 + c4 * 4 + 2] = v[2];
    tile[r * 65 + c4 * 4 + 3] = v[3];
  }
  __syncthreads();
  const int nl = t >> 2;     // local n 0..63
  const int kseg = t & 3;    // 16-k segment
  v4i o;
#pragma unroll
  for (int q = 0; q < 4; ++q) {
    const int kb = kseg * 16 + q * 4;
    int b0 = tile[(kb + 0) * 65 + nl] & 255;
    int b1 = tile[(kb + 1) * 65 + nl] & 255;
    int b2 = tile[(kb + 2) * 65 + nl] & 255;
    int b3 = tile[(kb + 3) * 65 + nl] & 255;
    o[q] = b0 | (b1 << 8) | (b2 << 16) | (b3 << 24);
  }
  *reinterpret_cast<v4i*>(wt + (size_t)(n0 + nl) * K_DIM + k0 + kseg * 16) = o;
}

// ---------------- kernel 5: int8 MFMA GEMM (m97 structure) ----------------
// C[M,N] = xq[M,K] * w_t[N,K]^T ; 128x128 tile, BK=64 bytes, 4 waves (2x2),
// each wave 64x64 via 4x4 frags of mfma_i32_16x16x64_i8.
__global__ __launch_bounds__(256) void gemm_i8(
    const signed char* __restrict__ xq, const signed char* __restrict__ wt,
    const float* __restrict__ scales, const float* __restrict__ bias,
    float* __restrict__ y) {
  __shared__ __align__(16) signed char lds_a[128 * 64];
  __shared__ __align__(16) signed char lds_b[128 * 64];
  const int tid = threadIdx.x;
  const int m0 = blockIdx.y * 128;
  const int n0 = blockIdx.x * 128;

  // staging map: thread -> (row, 16B seg). LDS dest is linear (tid*16) as
  // required by global_load_lds; the XOR swizzle is applied on the GLOBAL
  // source seg (both-sides rule, m201/m231).
  const int srow = tid >> 2;
  const int sseg = tid & 3;
  const int sgseg = sseg ^ ((srow ^ (srow >> 2)) & 3);
  const signed char* ga0 = xq + (size_t)(m0 + srow) * K_DIM + sgseg * 16;
  const signed char* gb0 = wt + (size_t)(n0 + srow) * K_DIM + sgseg * 16;
  signed char* la0 = lds_a + tid * 16;
  signed char* lb0 = lds_b + tid * 16;

  // fragment map: A lane l -> row l&15, k-chunk (l>>4)*16 (contiguous 16B)
  const int lane = tid & 63;
  const int wid = tid >> 6;
  const int wr = wid >> 1;
  const int wc = wid & 1;
  const int l15 = lane & 15;
  const int kc = lane >> 4;
  const int rslot = (kc ^ ((l15 ^ (l15 >> 2)) & 3)) * 16;  // same involution
  const signed char* pa = lds_a + (wr * 64 + l15) * 64 + rslot;
  const signed char* pb = lds_b + (wc * 64 + l15) * 64 + rslot;

  v4i acc[4][4] = {};

  for (int kt = 0; kt < K_DIM / 64; ++kt) {
    const int ko = kt * 64;
    llds16(ga0 + ko, la0);
    llds16(ga0 + ko + (size_t)64 * K_DIM, la0 + 4096);
    llds16(gb0 + ko, lb0);
    llds16(gb0 + ko + (size_t)64 * K_DIM, lb0 + 4096);
    __syncthreads();
    v4i a4[4], b4[4];
#pragma unroll
    for (int m = 0; m < 4; ++m) a4[m] = *reinterpret_cast<const v4i*>(pa + m * 1024);
#pragma unroll
    for (int n = 0; n < 4; ++n) b4[n] = *reinterpret_cast<const v4i*>(pb + n * 1024);
#pragma unroll
    for (int m = 0; m < 4; ++m)
#pragma unroll
      for (int n = 0; n < 4; ++n)
        acc[m][n] = __builtin_amdgcn_mfma_i32_16x16x64_i8(a4[m], b4[n], acc[m][n], 0, 0, 0);
    __syncthreads();
  }

  // epilogue: C/D 16x16 layout col=lane&15, row=(lane>>4)*4+reg
  const float s = scales[1];
#pragma unroll
  for (int n = 0; n < 4; ++n) {
    const int col = n0 + wc * 64 + n * 16 + l15;
    const float bv = bias[col];
#pragma unroll
    for (int m = 0; m < 4; ++m) {
      const int r0 = m0 + wr * 64 + m * 16 + kc * 4;
#pragma unroll
      for (int j = 0; j < 4; ++j)
        y[(size_t)(r0 + j) * N_DIM + col] = (float)acc[m][n][j] * s + bv;
    }
  }
}

// ---------------- fallback (small ws): sdot4 LDS GEMM reading w32 ----------------
#if defined(__has_builtin)
#if __has_builtin(__builtin_amdgcn_sdot4)
#define HAVE_SDOT4 1
#endif
#endif

static __device__ __forceinline__ int dot4(int a, int b, int c) {
#ifdef HAVE_SDOT4
  return __builtin_amdgcn_sdot4(a, b, c, false);
#else
  c += (int)(signed char)(a) * (int)(signed char)(b);
  c += (int)(signed char)(a >> 8) * (int)(signed char)(b >> 8);
  c += (int)(signed char)(a >> 16) * (int)(signed char)(b >> 16);
  c += (int)(signed char)(a >> 24) * (int)(signed char)(b >> 24);
  return c;
#endif
}

__global__ __launch_bounds__(256) void gemm_fallback(
    const signed char* __restrict__ xq, const int* __restrict__ w,
    const float* __restrict__ scales, const float* __restrict__ bias,
    float* __restrict__ y) {
  __shared__ int lds_a[64 * 17];  // [m][k-dword], pad 17
  __shared__ int lds_b[64 * 17];  // [n][k-dword], pad 17
  const int t = threadIdx.x;
  const int m0 = blockIdx.y * 64;
  const int n0 = blockIdx.x * 64;
  const int my = (t >> 4) * 4;
  const int nx = (t & 15) * 4;
  int acc[4][4] = {};
  for (int kt = 0; kt < K_DIM / 64; ++kt) {
    const int k0 = kt * 64;
    {  // A: 256 threads x 16B
      const int r = t >> 2, sg = t & 3;
      v4i v = *reinterpret_cast<const v4i*>(xq + (size_t)(m0 + r) * K_DIM + k0 + sg * 16);
      lds_a[r * 17 + sg * 4 + 0] = v[0];
      lds_a[r * 17 + sg * 4 + 1] = v[1];
      lds_a[r * 17 + sg * 4 + 2] = v[2];
      lds_a[r * 17 + sg * 4 + 3] = v[3];
    }
    {  // B: gather 4 strided k per dword, pack
      const int n = t & 63, bkk = (t >> 6) * 4;
#pragma unroll
      for (int q = 0; q < 4; ++q) {
        const int kk = bkk + q;
        int b0 = w[(size_t)(k0 + kk * 4 + 0) * N_DIM + n0 + n] & 255;
        int b1 = w[(size_t)(k0 + kk * 4 + 1) * N_DIM + n0 + n] & 255;
        int b2 = w[(size_t)(k0 + kk * 4 + 2) * N_DIM + n0 + n] & 255;
        int b3 = w[(size_t)(k0 + kk * 4 + 3) * N_DIM + n0 + n] & 255;
        lds_b[n * 17 + kk] = b0 | (b1 << 8) | (b2 << 16) | (b3 << 24);
      }
    }
    __syncthreads();
#pragma unroll
    for (int kk = 0; kk < 16; ++kk) {
      int a[4], b[4];
#pragma unroll
      for (int i = 0; i < 4; ++i) a[i] = lds_a[(my + i) * 17 + kk];
#pragma unroll
      for (int j = 0; j < 4; ++j) b[j] = lds_b[(nx + j) * 17 + kk];
#pragma unroll
      for (int i = 0; i < 4; ++i)
#pragma unroll
        for (int j = 0; j < 4; ++j) acc[i][j] = dot4(a[i], b[j], acc[i][j]);
    }
    __syncthreads();
  }
  const float s = scales[1];
#pragma unroll
  for (int i = 0; i < 4; ++i)
#pragma unroll
    for (int j = 0; j < 4; ++j)
      y[(size_t)(m0 + my + i) * N_DIM + n0 + nx + j] =
          (float)acc[i][j] * s + bias[n0 + nx + j];
}

// ---------------- launcher ----------------
extern "C" void kernel_launch(void* const* d_in, const int* in_sizes, int n_in,
                              void* d_out, int out_size, void* d_ws, size_t ws_size,
                              hipStream_t stream) {
  (void)in_sizes; (void)n_in; (void)out_size;
  const float* x = (const float*)d_in[0];
  const int* w = (const int*)d_in[1];  // int8 values stored as int32
  const float* bias = (const float*)d_in[2];
  const float* yscale = (const float*)d_in[3];
  float* y = (float*)d_out;
  char* ws = (char*)d_ws;
  float* scales = (float*)(ws);
  float* part = (float*)(ws + 1024);
  signed char* xq = (signed char*)(ws + WS_XQ_OFF);
  signed char* wt = (signed char*)(ws + WS_WT_OFF);

  if (ws_size < WS_SMALL_BYTES) return;  // cannot run without scratch

  absmax_kernel<<<1024, 256, 0, stream>>>(x, part);
  finalize_scale<<<1, 256, 0, stream>>>(part, yscale, scales);
  quant_kernel<<<2048, 256, 0, stream>>>(x, scales, xq);
  if (ws_size >= WS_FULL_BYTES) {
    transpose_pack<<<dim3(N_DIM / 64, K_DIM / 64), 256, 0, stream>>>(w, wt);
    gemm_i8<<<dim3(N_DIM / 128, M_DIM / 128), 256, 0, stream>>>(xq, wt, scales, bias, y);
  } else {
    gemm_fallback<<<dim3(N_DIM / 64, M_DIM / 64), 256, 0, stream>>>(xq, w, scales, bias, y);
  }
}

// Round 2
// 172.352 us; speedup vs baseline: 1.1125x; 1.1125x over previous
//
#include <hip/hip_runtime.h>
#include <stdint.h>

#define M_DIM 2048
#define K_DIM 4096
#define N_DIM 11008

typedef int v4i __attribute__((ext_vector_type(4)));

// ---------------- workspace layout ----------------
#define WS_XQ_OFF   65536ull
#define WS_WT_OFF   8454144ull
#define WS_FULL_BYTES (8454144ull + 45088768ull)
#define WS_SMALL_BYTES 8454144ull

static __device__ __forceinline__ void llds16(const void* g, void* l) {
  __builtin_amdgcn_global_load_lds(
      reinterpret_cast<const uint32_t __attribute__((address_space(1)))*>(
          reinterpret_cast<uintptr_t>(g)),
      reinterpret_cast<uint32_t __attribute__((address_space(3)))*>(
          reinterpret_cast<uintptr_t>(l)),
      16, 0, 0);
}

// ---------------- kernel 1: per-block abs-max over x ----------------
__global__ __launch_bounds__(256) void absmax_kernel(const float* __restrict__ x,
                                                     float* __restrict__ part) {
  __shared__ float red[256];
  const int g = blockIdx.x * 256 + threadIdx.x;
  const float4* x4 = reinterpret_cast<const float4*>(x);
  float m = 0.f;
#pragma unroll
  for (int i = 0; i < 8; ++i) {
    float4 v = x4[(size_t)i * 262144 + g];
    m = fmaxf(m, fmaxf(fmaxf(fabsf(v.x), fabsf(v.y)),
                       fmaxf(fabsf(v.z), fabsf(v.w))));
  }
  red[threadIdx.x] = m;
  __syncthreads();
  for (int s = 128; s > 0; s >>= 1) {
    if (threadIdx.x < s) red[threadIdx.x] = fmaxf(red[threadIdx.x], red[threadIdx.x + s]);
    __syncthreads();
  }
  if (threadIdx.x == 0) part[blockIdx.x] = red[0];
}

// ---------------- kernel 2: finalize scales ----------------
__global__ __launch_bounds__(256) void finalize_scale(const float* __restrict__ part,
                                                      const float* __restrict__ y_scale,
                                                      float* __restrict__ scales) {
  __shared__ float red[256];
  const int t = threadIdx.x;
  float m = fmaxf(fmaxf(part[t], part[t + 256]), fmaxf(part[t + 512], part[t + 768]));
  red[t] = m;
  __syncthreads();
  for (int s = 128; s > 0; s >>= 1) {
    if (t < s) red[t] = fmaxf(red[t], red[t + s]);
    __syncthreads();
  }
  if (t == 0) {
    float xs = red[0] * (1.0f / 128.0f);  // exact (pow2)
    scales[0] = xs;
    scales[1] = xs * y_scale[0];
  }
}

// ---------------- kernel 3: quantize x -> int8 ----------------
__global__ __launch_bounds__(256) void quant_kernel(const float* __restrict__ x,
                                                    const float* __restrict__ scales,
                                                    signed char* __restrict__ xq) {
  const float s = scales[0];
  const size_t t = (size_t)blockIdx.x * 256 + threadIdx.x;
  const float4* x4 = reinterpret_cast<const float4*>(x) + t * 4;
  v4i o;
#pragma unroll
  for (int i = 0; i < 4; ++i) {
    float4 v = x4[i];
    int q0 = (int)rintf(v.x / s);  // matches np.round (half-to-even)
    int q1 = (int)rintf(v.y / s);
    int q2 = (int)rintf(v.z / s);
    int q3 = (int)rintf(v.w / s);
    q0 = max(-128, min(127, q0));
    q1 = max(-128, min(127, q1));
    q2 = max(-128, min(127, q2));
    q3 = max(-128, min(127, q3));
    o[i] = (q0 & 255) | ((q1 & 255) << 8) | ((q2 & 255) << 16) | ((q3 & 255) << 24);
  }
  *reinterpret_cast<v4i*>(xq + t * 16) = o;
}

// ---------------- kernel 4: transpose+pack w32[K,N] -> w_t int8[N,K] ----------------
__global__ __launch_bounds__(256) void transpose_pack(const int* __restrict__ w,
                                                      signed char* __restrict__ wt) {
  __shared__ int tile[64 * 65];
  const int t = threadIdx.x;
  const int n0 = blockIdx.x * 64;
  const int k0 = blockIdx.y * 64;
#pragma unroll
  for (int p = 0; p < 4; ++p) {
    const int id = p * 256 + t;
    const int r = id >> 4;
    const int c4 = id & 15;
    v4i v = *reinterpret_cast<const v4i*>(w + (size_t)(k0 + r) * N_DIM + n0 + c4 * 4);
    tile[r * 65 + c4 * 4 + 0] = v[0];
    tile[r * 65 + c4 * 4 + 1] = v[1];
    tile[r * 65 + c4 * 4 + 2] = v[2];
    tile[r * 65 + c4 * 4 + 3] = v[3];
  }
  __syncthreads();
  const int nl = t >> 2;
  const int kseg = t & 3;
  v4i o;
#pragma unroll
  for (int q = 0; q < 4; ++q) {
    const int kb = kseg * 16 + q * 4;
    int b0 = tile[(kb + 0) * 65 + nl] & 255;
    int b1 = tile[(kb + 1) * 65 + nl] & 255;
    int b2 = tile[(kb + 2) * 65 + nl] & 255;
    int b3 = tile[(kb + 3) * 65 + nl] & 255;
    o[q] = b0 | (b1 << 8) | (b2 << 16) | (b3 << 24);
  }
  *reinterpret_cast<v4i*>(wt + (size_t)(n0 + nl) * K_DIM + k0 + kseg * 16) = o;
}

// ---------------- kernel 5: int8 MFMA GEMM v2 ----------------
// 128x256 tile, 4 waves (2M x 2N), per-wave 64x128, BK=64 bytes.
// Ring-3 LDS (3 x 24KB), depth-2 prefetch, counted vmcnt(6), raw s_barrier
// (one per K-iter, never a vmcnt(0) drain in the main loop).
#define TILE_B 24576          // per K-tile: A 128x64 (8KB) + B 256x64 (16KB)
#define NT_K   (K_DIM / 64)   // 64 K-tiles

__global__ __launch_bounds__(256, 2) void gemm_i8_v2(
    const signed char* __restrict__ xq, const signed char* __restrict__ wt,
    const float* __restrict__ scales, const float* __restrict__ bias,
    float* __restrict__ y) {
  __shared__ __align__(16) signed char smem[3 * TILE_B];
  const int tid = threadIdx.x;

  // T1: bijective XCD swizzle (688 blocks, 688%8==0) + column-major grid:
  // 16 consecutive m-tiles share one 1MB wt n-panel (L2-resident).
  const int bid = blockIdx.x;
  const int swz = (bid & 7) * 86 + (bid >> 3);
  const int m0 = (swz & 15) * 128;
  const int n0 = (swz >> 4) * 256;

  // staging map (proven in R1): thread -> (row = tid>>2, seg = tid&3);
  // LDS dest linear tid*16; XOR involution applied on the GLOBAL source seg.
  const int srow = tid >> 2;
  const int sseg = tid & 3;
  const int sgseg = sseg ^ ((srow ^ (srow >> 2)) & 3);
  const signed char* gA = xq + (size_t)(m0 + srow) * K_DIM + sgseg * 16;
  const signed char* gB = wt + (size_t)(n0 + srow) * K_DIM + sgseg * 16;
  signed char* const l0 = smem + tid * 16;

#define STAGE(kt, soff)                                                   \
  do {                                                                    \
    const size_t ko_ = (size_t)(kt) * 64;                                 \
    llds16(gA + ko_,                       l0 + (soff));                  \
    llds16(gA + ko_ + (size_t)64 * K_DIM,  l0 + (soff) + 4096);           \
    llds16(gB + ko_,                       l0 + (soff) + 8192);           \
    llds16(gB + ko_ + (size_t)64 * K_DIM,  l0 + (soff) + 12288);          \
    llds16(gB + ko_ + (size_t)128 * K_DIM, l0 + (soff) + 16384);          \
    llds16(gB + ko_ + (size_t)192 * K_DIM, l0 + (soff) + 20480);          \
  } while (0)

  // fragment map (proven in R1): lane l -> row l&15 (+16*frag), k-chunk l>>4,
  // LDS seg = kc ^ swz(row) (same involution as staging source).
  const int lane = tid & 63;
  const int wid = tid >> 6;
  const int wm = wid >> 1;   // 0..1 -> 64-row half
  const int wn = wid & 1;    // 0..1 -> 128-col half
  const int l15 = lane & 15;
  const int kc = lane >> 4;
  const int rslot = (kc ^ ((l15 ^ (l15 >> 2)) & 3)) * 16;
  const int cA = (wm * 64 + l15) * 64 + rslot;                 // + m*1024
  const int cB = 8192 + (wn * 128 + l15) * 64 + rslot;         // + n*1024

  v4i acc[4][8] = {};

#define COMPUTE(roff)                                                        \
  do {                                                                       \
    const signed char* bp_ = smem + (roff);                                  \
    v4i a_[4], b_[8];                                                        \
    _Pragma("unroll")                                                        \
    for (int m_ = 0; m_ < 4; ++m_)                                           \
      a_[m_] = *reinterpret_cast<const v4i*>(bp_ + cA + m_ * 1024);          \
    _Pragma("unroll")                                                        \
    for (int n_ = 0; n_ < 8; ++n_)                                           \
      b_[n_] = *reinterpret_cast<const v4i*>(bp_ + cB + n_ * 1024);          \
    _Pragma("unroll")                                                        \
    for (int m_ = 0; m_ < 4; ++m_)                                           \
      _Pragma("unroll")                                                      \
      for (int n_ = 0; n_ < 8; ++n_)                                         \
        acc[m_][n_] = __builtin_amdgcn_mfma_i32_16x16x64_i8(                 \
            a_[m_], b_[n_], acc[m_][n_], 0, 0, 0);                           \
  } while (0)

  // prologue: stage tiles 0,1 into buf0,buf1 (12 loads/thread in flight)
  STAGE(0, 0);
  STAGE(1, TILE_B);

  int rOff = 0;
  int sOff = 2 * TILE_B;
  // main loop: iters 0..61 stage tile t+2
  for (int t = 0; t < NT_K - 2; ++t) {
    // retire exactly tile t's 6 loads (outstanding before wait: t,t+1 = 12)
    asm volatile("s_waitcnt vmcnt(6)" ::: "memory");
    __builtin_amdgcn_s_barrier();          // all waves' tile-t LDS now valid
    __builtin_amdgcn_sched_barrier(0);
    STAGE(t + 2, sOff);                    // targets buf freed at iter t-1
    COMPUTE(rOff);
    rOff = (rOff == 2 * TILE_B) ? 0 : rOff + TILE_B;
    sOff = (sOff == 2 * TILE_B) ? 0 : sOff + TILE_B;
  }
  // iter 62: outstanding {62,63}=12 -> vmcnt(6) retires 62; no stage
  asm volatile("s_waitcnt vmcnt(6)" ::: "memory");
  __builtin_amdgcn_s_barrier();
  __builtin_amdgcn_sched_barrier(0);
  COMPUTE(rOff);
  rOff = (rOff == 2 * TILE_B) ? 0 : rOff + TILE_B;
  // iter 63: drain the last tile
  asm volatile("s_waitcnt vmcnt(0)" ::: "memory");
  __builtin_amdgcn_s_barrier();
  __builtin_amdgcn_sched_barrier(0);
  COMPUTE(rOff);

#undef STAGE
#undef COMPUTE

  // epilogue: C/D 16x16 layout col=lane&15, row=(lane>>4)*4+reg (R1-proven)
  const float s = scales[1];
#pragma unroll
  for (int n = 0; n < 8; ++n) {
    const int col = n0 + wn * 128 + n * 16 + l15;
    const float bv = bias[col];
#pragma unroll
    for (int m = 0; m < 4; ++m) {
      const int r0 = m0 + wm * 64 + m * 16 + kc * 4;
#pragma unroll
      for (int j = 0; j < 4; ++j)
        y[(size_t)(r0 + j) * N_DIM + col] = (float)acc[m][n][j] * s + bv;
    }
  }
}

// ---------------- fallback (small ws): sdot4 LDS GEMM reading w32 ----------------
#if defined(__has_builtin)
#if __has_builtin(__builtin_amdgcn_sdot4)
#define HAVE_SDOT4 1
#endif
#endif

static __device__ __forceinline__ int dot4(int a, int b, int c) {
#ifdef HAVE_SDOT4
  return __builtin_amdgcn_sdot4(a, b, c, false);
#else
  c += (int)(signed char)(a) * (int)(signed char)(b);
  c += (int)(signed char)(a >> 8) * (int)(signed char)(b >> 8);
  c += (int)(signed char)(a >> 16) * (int)(signed char)(b >> 16);
  c += (int)(signed char)(a >> 24) * (int)(signed char)(b >> 24);
  return c;
#endif
}

__global__ __launch_bounds__(256) void gemm_fallback(
    const signed char* __restrict__ xq, const int* __restrict__ w,
    const float* __restrict__ scales, const float* __restrict__ bias,
    float* __restrict__ y) {
  __shared__ int lds_a[64 * 17];
  __shared__ int lds_b[64 * 17];
  const int t = threadIdx.x;
  const int m0 = blockIdx.y * 64;
  const int n0 = blockIdx.x * 64;
  const int my = (t >> 4) * 4;
  const int nx = (t & 15) * 4;
  int acc[4][4] = {};
  for (int kt = 0; kt < K_DIM / 64; ++kt) {
    const int k0 = kt * 64;
    {
      const int r = t >> 2, sg = t & 3;
      v4i v = *reinterpret_cast<const v4i*>(xq + (size_t)(m0 + r) * K_DIM + k0 + sg * 16);
      lds_a[r * 17 + sg * 4 + 0] = v[0];
      lds_a[r * 17 + sg * 4 + 1] = v[1];
      lds_a[r * 17 + sg * 4 + 2] = v[2];
      lds_a[r * 17 + sg * 4 + 3] = v[3];
    }
    {
      const int n = t & 63, bkk = (t >> 6) * 4;
#pragma unroll
      for (int q = 0; q < 4; ++q) {
        const int kk = bkk + q;
        int b0 = w[(size_t)(k0 + kk * 4 + 0) * N_DIM + n0 + n] & 255;
        int b1 = w[(size_t)(k0 + kk * 4 + 1) * N_DIM + n0 + n] & 255;
        int b2 = w[(size_t)(k0 + kk * 4 + 2) * N_DIM + n0 + n] & 255;
        int b3 = w[(size_t)(k0 + kk * 4 + 3) * N_DIM + n0 + n] & 255;
        lds_b[n * 17 + kk] = b0 | (b1 << 8) | (b2 << 16) | (b3 << 24);
      }
    }
    __syncthreads();
#pragma unroll
    for (int kk = 0; kk < 16; ++kk) {
      int a[4], b[4];
#pragma unroll
      for (int i = 0; i < 4; ++i) a[i] = lds_a[(my + i) * 17 + kk];
#pragma unroll
      for (int j = 0; j < 4; ++j) b[j] = lds_b[(nx + j) * 17 + kk];
#pragma unroll
      for (int i = 0; i < 4; ++i)
#pragma unroll
        for (int j = 0; j < 4; ++j) acc[i][j] = dot4(a[i], b[j], acc[i][j]);
    }
    __syncthreads();
  }
  const float s = scales[1];
#pragma unroll
  for (int i = 0; i < 4; ++i)
#pragma unroll
    for (int j = 0; j < 4; ++j)
      y[(size_t)(m0 + my + i) * N_DIM + n0 + nx + j] =
          (float)acc[i][j] * s + bias[n0 + nx + j];
}

// ---------------- launcher ----------------
extern "C" void kernel_launch(void* const* d_in, const int* in_sizes, int n_in,
                              void* d_out, int out_size, void* d_ws, size_t ws_size,
                              hipStream_t stream) {
  (void)in_sizes; (void)n_in; (void)out_size;
  const float* x = (const float*)d_in[0];
  const int* w = (const int*)d_in[1];  // int8 values stored as int32
  const float* bias = (const float*)d_in[2];
  const float* yscale = (const float*)d_in[3];
  float* y = (float*)d_out;
  char* ws = (char*)d_ws;
  float* scales = (float*)(ws);
  float* part = (float*)(ws + 1024);
  signed char* xq = (signed char*)(ws + WS_XQ_OFF);
  signed char* wt = (signed char*)(ws + WS_WT_OFF);

  if (ws_size < WS_SMALL_BYTES) return;

  absmax_kernel<<<1024, 256, 0, stream>>>(x, part);
  finalize_scale<<<1, 256, 0, stream>>>(part, yscale, scales);
  quant_kernel<<<2048, 256, 0, stream>>>(x, scales, xq);
  if (ws_size >= WS_FULL_BYTES) {
    transpose_pack<<<dim3(N_DIM / 64, K_DIM / 64), 256, 0, stream>>>(w, wt);
    gemm_i8_v2<<<(M_DIM / 128) * (N_DIM / 256), 256, 0, stream>>>(xq, wt, scales, bias, y);
  } else {
    gemm_fallback<<<dim3(N_DIM / 64, M_DIM / 64), 256, 0, stream>>>(xq, w, scales, bias, y);
  }
}